// Round 5
// baseline (24347.600 us; speedup 1.0000x reference)
//
#include <hip/hip_runtime.h>
#include <cstdint>
#include <cstddef>

// ---------------- problem constants ----------------
#define TSTEPS 2000
#define NB     256      // batch
#define HID    128
#define CIN    14
#define NGRP   64       // row groups
#define RG     4        // rows per group
#define BPG    4        // blocks per group (h-quarters, each does L1+L2)

// ---------------- workspace layout (bytes) ----------------
#define OFF_CNT   0ull                     // 256 flags * 32B = 8192
#define OFF_M1WS  8192ull                  // [2][64][128k][4r] f32 = 262144
#define OFF_M2WS  (OFF_M1WS + 262144ull)   // [2][64][128k][4r] f32
#define OFF_SPKW  (OFF_M2WS + 262144ull)   // [2][64][4r][4q] u32 = 8192
#define OFF_FEAT  (OFF_SPKW + 8192ull)     // [256][128] f32 = 131072
#define OFF_AB    (OFF_FEAT + 131072ull)   // a[64], b[64] = 512
#define OFF_PART  (OFF_AB   + 512ull)      // [2304][64][2] f32 = 1179648
#define OFF_MASK  (OFF_PART + 1179648ull)  // [2000][256] u64 = 4096000
#define ZERO_WORDS 133120                  // flags + m1ws + m2ws

// ============================================================
// K0: zero flags + state buffers (every launch, for graph replay)
// ============================================================
__global__ __launch_bounds__(256) void k0_zero(unsigned* ws) {
  int i = blockIdx.x * 256 + threadIdx.x;
  if (i < ZERO_WORDS) ws[i] = 0u;
}

// ============================================================
// K1: conv1d -> per-(b,tile) partial sum/sumsq for BN
// ============================================================
__global__ __launch_bounds__(256) void k1_stats(const float* __restrict__ x,
                                                const float* __restrict__ cw,
                                                float* __restrict__ part) {
  __shared__ float xLds[244 * CIN];
  __shared__ float cwLds[64 * 70];
  __shared__ float red[2][4][64];
  const int b = blockIdx.x, tile = blockIdx.y;
  const int base = tile * 240;
  for (int f = threadIdx.x; f < 244 * CIN; f += 256) {
    int u = f / CIN, ci = f - u * CIN;
    int tp = base + u - 2;
    xLds[f] = (tp >= 0 && tp < TSTEPS) ? x[((size_t)tp * NB + b) * CIN + ci] : 0.0f;
  }
  for (int f = threadIdx.x; f < 64 * 70; f += 256) cwLds[f] = cw[f];
  __syncthreads();

  const int co = threadIdx.x & 63, tq = threadIdx.x >> 6;
  float cwr[70];
#pragma unroll
  for (int s = 0; s < 70; ++s) cwr[s] = cwLds[co * 70 + s];
  float xw[5][CIN];
  const int u0 = tq * 60;
#pragma unroll
  for (int r = 0; r < 4; ++r)
#pragma unroll
    for (int ci = 0; ci < CIN; ++ci) xw[r][ci] = xLds[(u0 + r) * CIN + ci];

  float s1 = 0.0f, s2 = 0.0f;
  const int tbase = base + tq * 60;
  for (int i5 = 0; i5 < 60; i5 += 5) {
#pragma unroll
    for (int s = 0; s < 5; ++s) {
#pragma unroll
      for (int ci = 0; ci < CIN; ++ci)
        xw[(s + 4) % 5][ci] = xLds[(u0 + i5 + s + 4) * CIN + ci];
      float y = 0.0f;
#pragma unroll
      for (int kk = 0; kk < 5; ++kk)
#pragma unroll
        for (int ci = 0; ci < CIN; ++ci)
          y += xw[(s + kk) % 5][ci] * cwr[ci * 5 + kk];
      if (tbase + i5 + s < TSTEPS) { s1 += y; s2 += y * y; }
    }
  }
  red[0][tq][co] = s1; red[1][tq][co] = s2;
  __syncthreads();
  if (threadIdx.x < 64) {
    float a1 = red[0][0][co] + red[0][1][co] + red[0][2][co] + red[0][3][co];
    float a2 = red[1][0][co] + red[1][1][co] + red[1][2][co] + red[1][3][co];
    int blk = tile * NB + b;
    part[blk * 128 + co * 2 + 0] = a1;
    part[blk * 128 + co * 2 + 1] = a2;
  }
}

// K1b: deterministic fixed-order reduction of partials -> a[co], b[co]
__global__ __launch_bounds__(256) void k1b_reduce(const float* __restrict__ gamma,
                           const float* __restrict__ beta,
                           const float* __restrict__ part, float* __restrict__ ab) {
  __shared__ float red[2][4][64];
  const int co = threadIdx.x & 63, pt = threadIdx.x >> 6;
  float s1 = 0.0f, s2 = 0.0f;
  for (int blk = pt * 576; blk < pt * 576 + 576; ++blk) {
    s1 += part[blk * 128 + co * 2 + 0];
    s2 += part[blk * 128 + co * 2 + 1];
  }
  red[0][pt][co] = s1; red[1][pt][co] = s2;
  __syncthreads();
  if (threadIdx.x < 64) {
    float a1 = red[0][0][co] + red[0][1][co] + red[0][2][co] + red[0][3][co];
    float a2 = red[1][0][co] + red[1][1][co] + red[1][2][co] + red[1][3][co];
    const float N = (float)TSTEPS * (float)NB;
    float mu = a1 / N;
    float var = a2 / N - mu * mu;
    float rstd = 1.0f / sqrtf(var + 1e-5f);
    float a = gamma[co] * rstd;
    ab[co] = a;
    ab[64 + co] = beta[co] - mu * a;
  }
}

// ============================================================
// K2: conv1d -> BN -> spike -> pack 64 channel bits into u64 per (t,b)
// ============================================================
__global__ __launch_bounds__(256) void k2_spike(const float* __restrict__ x,
                                                const float* __restrict__ cw,
                                                const float* __restrict__ thrp,
                                                const float* __restrict__ ab,
                                                unsigned long long* __restrict__ masks) {
  __shared__ float xLds[244 * CIN];
  __shared__ float cwLds[64 * 70];
  const int b = blockIdx.x, tile = blockIdx.y;
  const int base = tile * 240;
  for (int f = threadIdx.x; f < 244 * CIN; f += 256) {
    int u = f / CIN, ci = f - u * CIN;
    int tp = base + u - 2;
    xLds[f] = (tp >= 0 && tp < TSTEPS) ? x[((size_t)tp * NB + b) * CIN + ci] : 0.0f;
  }
  for (int f = threadIdx.x; f < 64 * 70; f += 256) cwLds[f] = cw[f];
  __syncthreads();

  const int co = threadIdx.x & 63, tq = threadIdx.x >> 6;
  const float thr = thrp[0];
  const float aC = ab[co], bC = ab[64 + co];
  float cwr[70];
#pragma unroll
  for (int s = 0; s < 70; ++s) cwr[s] = cwLds[co * 70 + s];
  float xw[5][CIN];
  const int u0 = tq * 60;
#pragma unroll
  for (int r = 0; r < 4; ++r)
#pragma unroll
    for (int ci = 0; ci < CIN; ++ci) xw[r][ci] = xLds[(u0 + r) * CIN + ci];

  const int tbase = base + tq * 60;
  for (int i5 = 0; i5 < 60; i5 += 5) {
#pragma unroll
    for (int s = 0; s < 5; ++s) {
#pragma unroll
      for (int ci = 0; ci < CIN; ++ci)
        xw[(s + 4) % 5][ci] = xLds[(u0 + i5 + s + 4) * CIN + ci];
      float y = 0.0f;
#pragma unroll
      for (int kk = 0; kk < 5; ++kk)
#pragma unroll
        for (int ci = 0; ci < CIN; ++ci)
          y += xw[(s + kk) % 5][ci] * cwr[ci * 5 + kk];
      int t = tbase + i5 + s;
      if (t < TSTEPS) {
        float bn = y * aC + bC;
        unsigned long long m = __ballot(bn - thr > 0.0f);  // lane i = channel i
        if (co == 0) masks[(size_t)t * NB + b] = m;
      }
    }
  }
}

// ============================================================
// KP: fused persistent two-layer SLSTM, software-pipelined (L1 step p +
// L2 step p-1 per phase), fence-free flag sync (relaxed-agent atomics).
// Round-5 changes:
//  - GEMM remap: 2 gate rows per thread, 8-way k-interleave (k = m*8+kq).
//    Same 112 weight VGPRs, HALF the ds_read_b128 (56/thread), each 16B
//    A-read now feeds 8 FMAs; per-wave read = 8 contiguous 16B chunks
//    (8-way broadcast, conflict-free).
//  - State layout [k][row] -> staging is 2 coalesced scalar atomic loads.
//  - 80KB dynamic LDS forces 1 block/CU (kills the 2-blocks-on-one-CU
//    47ms mode: group barrier coupled the grid to a half-rate CU).
//  - busy-wait poll without s_sleep (avoid idle-hint downclocking; poll
//    rate is naturally limited by ~600cy L3 load latency).
// ============================================================
__global__ __launch_bounds__(512) void kp_fused(char* ws,
    const float* __restrict__ w_ih1, const float* __restrict__ w_hh1,
    const float* __restrict__ b_ih1, const float* __restrict__ b_hh1,
    const float* __restrict__ thr1p,
    const float* __restrict__ w_ih2, const float* __restrict__ w_hh2,
    const float* __restrict__ b_ih2, const float* __restrict__ b_hh2,
    const float* __restrict__ thr2p) {
  extern __shared__ float dynbuf[];        // 80KB requested at launch
  float* A1 = dynbuf;                      // [192 k][4 r]
  float* A2 = dynbuf + 768;                // [256 k][4 r]
  __shared__ float gate1L[128 * 5];        // stride 5 breaks bank pattern
  __shared__ float gate2L[128 * 5];
  __shared__ float biasL1[128], biasL2[128];

  const int tid = threadIdx.x;
  const int bid = blockIdx.x;
  const int g = bid & 63;          // group; peers bid = g+64k
  const int q = bid >> 6;          // h-quarter 0..3
  const int lane = tid & 63, wv = tid >> 6;
  const int u = lane & 7, kq = lane >> 3;  // 8-way k-split, u -> 2 j's
  const int jl0 = wv * 16 + u * 2;         // local gate-row base (0..126)

  unsigned* flags = (unsigned*)(ws + OFF_CNT);   // [(g*4+q)*8], 32B apart
  float* m1ws = (float*)(ws + OFF_M1WS);
  float* m2ws = (float*)(ws + OFF_M2WS);
  unsigned* spkw = (unsigned*)(ws + OFF_SPKW);
  float* feat = (float*)(ws + OFF_FEAT);
  const unsigned long long* masks = (const unsigned long long*)(ws + OFF_MASK);

  // ---- one-time: weights -> registers (k = m*8 + kq interleave) ----
  float wr1[2][24], wr2[2][32];
#pragma unroll
  for (int jj = 0; jj < 2; ++jj) {
    const int j = jl0 + jj;                // 0..127
    const int a = j >> 5, hl = j & 31;
    const int grow = a * 128 + q * 32 + hl;
#pragma unroll
    for (int m = 0; m < 24; ++m) {
      int k = m * 8 + kq;
      wr1[jj][m] = (k < 64) ? w_ih1[grow * 64 + k] : w_hh1[grow * 128 + (k - 64)];
    }
#pragma unroll
    for (int m = 0; m < 32; ++m) {
      int k = m * 8 + kq;
      wr2[jj][m] = (k < 128) ? w_ih2[grow * 128 + k] : w_hh2[grow * 128 + (k - 128)];
    }
  }
  if (tid < 128) {
    int aa = tid >> 5, h2 = tid & 31;
    int gr = aa * 128 + q * 32 + h2;
    biasL1[tid] = b_ih1[gr] + b_hh1[gr];
    biasL2[tid] = b_ih2[gr] + b_hh2[gr];
  }
  const float thr1 = thr1p[0], thr2 = thr2p[0];
  const int cr = tid >> 5, chl = tid & 31;   // cell mapping for tid<128
  float syn1 = 0.0f, mem1 = 0.0f, syn2 = 0.0f, mem2 = 0.0f, facc = 0.0f;
  __syncthreads();

  // conv-spike mask for step 0 (row = tid&3)
  unsigned long long mrow = masks[(size_t)0 * NB + g * RG + (tid & 3)];

  for (int p = 0; p <= TSTEPS; ++p) {
    const int rb1 = (p + 1) & 1;   // parity of p-1
    const int wb = p & 1;          // parity of p

    // ---- single coalesced load burst ----
    if (tid < 256) {               // A1 k<64: conv spike bits (k=tid>>2,e=tid&3)
      A1[tid] = (float)((mrow >> (tid >> 2)) & 1ull);
    }
    {                              // A1 k in [64,192): m1(p-1), flat coalesced
      float v = __hip_atomic_load(&m1ws[(size_t)(rb1 * 64 + g) * 512 + tid],
                                  __ATOMIC_RELAXED, __HIP_MEMORY_SCOPE_AGENT);
      A1[256 + tid] = v;
    }
    {                              // A2 k<128: spk1(p-1) bits
      int k = tid >> 2, e = tid & 3;
      unsigned uu = __hip_atomic_load(&spkw[((rb1 * 64 + g) * 4 + e) * 4 + (k >> 5)],
                                      __ATOMIC_RELAXED, __HIP_MEMORY_SCOPE_AGENT);
      A2[tid] = (float)((uu >> (k & 31)) & 1u);
    }
    {                              // A2 k in [128,256): m2(p-2), flat coalesced
      float v = __hip_atomic_load(&m2ws[(size_t)(wb * 64 + g) * 512 + tid],
                                  __ATOMIC_RELAXED, __HIP_MEMORY_SCOPE_AGENT);
      A2[512 + tid] = v;
    }
    if (p + 1 < TSTEPS) mrow = masks[(size_t)(p + 1) * NB + g * RG + (tid & 3)];
    __syncthreads();

    // ---- GEMM1: K=192, k = m*8+kq, 2 j rows per thread ----
    {
      float ac[2][4];
#pragma unroll
      for (int jj = 0; jj < 2; ++jj)
#pragma unroll
        for (int r = 0; r < 4; ++r) ac[jj][r] = 0.0f;
      const float4* A1v = (const float4*)A1;
#pragma unroll
      for (int m = 0; m < 24; ++m) {
        float4 av = A1v[m * 8 + kq];
        float w0 = wr1[0][m], w1 = wr1[1][m];
        ac[0][0] += w0 * av.x; ac[0][1] += w0 * av.y;
        ac[0][2] += w0 * av.z; ac[0][3] += w0 * av.w;
        ac[1][0] += w1 * av.x; ac[1][1] += w1 * av.y;
        ac[1][2] += w1 * av.z; ac[1][3] += w1 * av.w;
      }
#pragma unroll
      for (int jj = 0; jj < 2; ++jj)
#pragma unroll
        for (int r = 0; r < 4; ++r) {
          float v = ac[jj][r];
          v += __shfl_xor(v, 8); v += __shfl_xor(v, 16); v += __shfl_xor(v, 32);
          ac[jj][r] = v;
        }
      if (kq == 0) {
#pragma unroll
        for (int jj = 0; jj < 2; ++jj)
#pragma unroll
          for (int r = 0; r < 4; ++r)
            gate1L[(jl0 + jj) * 5 + r] = ac[jj][r];
      }
    }
    // ---- GEMM2: K=256 ----
    {
      float ac[2][4];
#pragma unroll
      for (int jj = 0; jj < 2; ++jj)
#pragma unroll
        for (int r = 0; r < 4; ++r) ac[jj][r] = 0.0f;
      const float4* A2v = (const float4*)A2;
#pragma unroll
      for (int m = 0; m < 32; ++m) {
        float4 av = A2v[m * 8 + kq];
        float w0 = wr2[0][m], w1 = wr2[1][m];
        ac[0][0] += w0 * av.x; ac[0][1] += w0 * av.y;
        ac[0][2] += w0 * av.z; ac[0][3] += w0 * av.w;
        ac[1][0] += w1 * av.x; ac[1][1] += w1 * av.y;
        ac[1][2] += w1 * av.z; ac[1][3] += w1 * av.w;
      }
#pragma unroll
      for (int jj = 0; jj < 2; ++jj)
#pragma unroll
        for (int r = 0; r < 4; ++r) {
          float v = ac[jj][r];
          v += __shfl_xor(v, 8); v += __shfl_xor(v, 16); v += __shfl_xor(v, 32);
          ac[jj][r] = v;
        }
      if (kq == 0) {
#pragma unroll
        for (int jj = 0; jj < 2; ++jj)
#pragma unroll
          for (int r = 0; r < 4; ++r)
            gate2L[(jl0 + jj) * 5 + r] = ac[jj][r];
      }
    }
    __syncthreads();

    // ---- cell1 (step p) + publish m1(p), spk1(p) ----
    if (tid < 128 && p < TSTEPS) {
      float g0 = biasL1[chl]       + gate1L[(chl) * 5 + cr];
      float g1 = biasL1[32 + chl]  + gate1L[(32 + chl) * 5 + cr];
      float g2 = biasL1[64 + chl]  + gate1L[(64 + chl) * 5 + cr];
      float g3 = biasL1[96 + chl]  + gate1L[(96 + chl) * 5 + cr];
      float rst = (mem1 - thr1 > 0.0f) ? thr1 : 0.0f;
      float ig = 1.0f / (1.0f + expf(-g0));
      float fg = 1.0f / (1.0f + expf(-g1));
      float gg = tanhf(g2);
      float og = 1.0f / (1.0f + expf(-g3));
      float cn = fg * syn1 + ig * gg;
      float mn = og * tanhf(cn) - rst;
      syn1 = cn; mem1 = mn;
      __hip_atomic_store(&m1ws[(size_t)(wb * 64 + g) * 512 + (q * 32 + chl) * 4 + cr],
                         mn, __ATOMIC_RELAXED, __HIP_MEMORY_SCOPE_AGENT);
      unsigned long long bal = __ballot(mn - thr1 > 0.0f);
      if (lane == 0)
        __hip_atomic_store(&spkw[((wb * 64 + g) * 4 + (wv * 2 + 0)) * 4 + q],
                           (unsigned)(bal & 0xffffffffull),
                           __ATOMIC_RELAXED, __HIP_MEMORY_SCOPE_AGENT);
      if (lane == 32)
        __hip_atomic_store(&spkw[((wb * 64 + g) * 4 + (wv * 2 + 1)) * 4 + q],
                           (unsigned)(bal >> 32),
                           __ATOMIC_RELAXED, __HIP_MEMORY_SCOPE_AGENT);
    }
    // ---- cell2 (step p-1) + publish m2(p-1) + feature accum ----
    if (tid < 128 && p >= 1) {
      float g0 = biasL2[chl]       + gate2L[(chl) * 5 + cr];
      float g1 = biasL2[32 + chl]  + gate2L[(32 + chl) * 5 + cr];
      float g2 = biasL2[64 + chl]  + gate2L[(64 + chl) * 5 + cr];
      float g3 = biasL2[96 + chl]  + gate2L[(96 + chl) * 5 + cr];
      float rst = (mem2 - thr2 > 0.0f) ? thr2 : 0.0f;
      float ig = 1.0f / (1.0f + expf(-g0));
      float fg = 1.0f / (1.0f + expf(-g1));
      float gg = tanhf(g2);
      float og = 1.0f / (1.0f + expf(-g3));
      float cn = fg * syn2 + ig * gg;
      float mn = og * tanhf(cn) - rst;
      syn2 = cn; mem2 = mn;
      __hip_atomic_store(&m2ws[(size_t)(rb1 * 64 + g) * 512 + (q * 32 + chl) * 4 + cr],
                         mn, __ATOMIC_RELAXED, __HIP_MEMORY_SCOPE_AGENT);
      facc += mn;
    }
    __syncthreads();  // drains vmcnt(0): all publishes ACKed at coherence point

    // ---- ONE distributed-flag barrier per phase (fence-free, no RMW) ----
    if (p < TSTEPS) {
      if (tid == 0)
        __hip_atomic_store(&flags[(g * 4 + q) * 8], (unsigned)(p + 1),
                           __ATOMIC_RELAXED, __HIP_MEMORY_SCOPE_AGENT);
      if (tid < 4) {
        while (__hip_atomic_load(&flags[(g * 4 + tid) * 8],
                                 __ATOMIC_RELAXED, __HIP_MEMORY_SCOPE_AGENT)
               < (unsigned)(p + 1)) { /* busy poll; load latency paces it */ }
      }
      __syncthreads();
    }
  }

  if (tid < 128)
    feat[(g * RG + cr) * 128 + q * 32 + chl] = facc * (1.0f / (float)TSTEPS);
}

// ============================================================
// K3: head — gesture + (binary) domain_hidden -> domain
// ============================================================
__global__ __launch_bounds__(128) void k3_head(const float* __restrict__ feat,
    const float* __restrict__ gw, const float* __restrict__ gb,
    const float* __restrict__ d1w, const float* __restrict__ d1b,
    const float* __restrict__ thrdp,
    const float* __restrict__ d2w, const float* __restrict__ d2b,
    float* __restrict__ out) {
  __shared__ float fL[128];
  __shared__ float dh[64];
  const int b = blockIdx.x, t = threadIdx.x;
  fL[t] = feat[b * 128 + t];
  __syncthreads();
  if (t < 64) {
    float s = d1b[t];
    for (int k = 0; k < 128; ++k) s += d1w[t * 128 + k] * fL[k];
    dh[t] = (s - thrdp[0] > 0.0f) ? 1.0f : 0.0f;
  }
  __syncthreads();
  if (t < 8) {
    float s = gb[t];
    for (int k = 0; k < 128; ++k) s += gw[t * 128 + k] * fL[k];
    out[b * 8 + t] = s;
  }
  if (t >= 64 && t < 74) {
    const int o = t - 64;
    float s = d2b[o];
    for (int k = 0; k < 64; ++k) s += d2w[o * 64 + k] * dh[k];
    out[2048 + b * 10 + o] = s;
  }
}

// ============================================================
extern "C" void kernel_launch(void* const* d_in, const int* in_sizes, int n_in,
                              void* d_out, int out_size, void* d_ws, size_t ws_size,
                              hipStream_t stream) {
  const float* x      = (const float*)d_in[0];
  const float* conv_w = (const float*)d_in[1];
  const float* bn_g   = (const float*)d_in[2];
  const float* bn_b   = (const float*)d_in[3];
  const float* thrl1  = (const float*)d_in[4];
  const float* w_ih1  = (const float*)d_in[5];
  const float* w_hh1  = (const float*)d_in[6];
  const float* b_ih1  = (const float*)d_in[7];
  const float* b_hh1  = (const float*)d_in[8];
  const float* thr1   = (const float*)d_in[9];
  const float* w_ih2  = (const float*)d_in[10];
  const float* w_hh2  = (const float*)d_in[11];
  const float* b_ih2  = (const float*)d_in[12];
  const float* b_hh2  = (const float*)d_in[13];
  const float* thr2   = (const float*)d_in[14];
  const float* fc_g_w = (const float*)d_in[15];
  const float* fc_g_b = (const float*)d_in[16];
  const float* fc_d1w = (const float*)d_in[17];
  const float* fc_d1b = (const float*)d_in[18];
  const float* thrdom = (const float*)d_in[19];
  const float* fc_d2w = (const float*)d_in[20];
  const float* fc_d2b = (const float*)d_in[21];
  float* out = (float*)d_out;
  char* ws = (char*)d_ws;

  k0_zero<<<(ZERO_WORDS + 255) / 256, 256, 0, stream>>>((unsigned*)ws);
  k1_stats<<<dim3(NB, 9), 256, 0, stream>>>(x, conv_w, (float*)(ws + OFF_PART));
  k1b_reduce<<<1, 256, 0, stream>>>(bn_g, bn_b, (const float*)(ws + OFF_PART),
                                    (float*)(ws + OFF_AB));
  k2_spike<<<dim3(NB, 9), 256, 0, stream>>>(x, conv_w, thrl1,
                                            (const float*)(ws + OFF_AB),
                                            (unsigned long long*)(ws + OFF_MASK));
  // 80KB dynamic LDS: forces exactly 1 persistent block per CU
  kp_fused<<<NGRP * BPG, 512, 81920, stream>>>(ws, w_ih1, w_hh1, b_ih1, b_hh1, thr1,
                                               w_ih2, w_hh2, b_ih2, b_hh2, thr2);
  k3_head<<<NB, 128, 0, stream>>>((const float*)(ws + OFF_FEAT), fc_g_w, fc_g_b,
                                  fc_d1w, fc_d1b, thrdom, fc_d2w, fc_d2b, out);
}

// Round 6
// 23330.717 us; speedup vs baseline: 1.0436x; 1.0436x over previous
//
#include <hip/hip_runtime.h>
#include <cstdint>
#include <cstddef>

// ---------------- problem constants ----------------
#define TSTEPS 2000
#define NB     256      // batch
#define HID    128
#define CIN    14
#define NGRP   64       // row groups
#define RG     4        // rows per group
#define BPG    4        // blocks per group (h-quarters, each does L1+L2)

// ---------------- workspace layout (bytes) ----------------
#define OFF_CNT   0ull                     // 256 flags * 32B = 8192
#define OFF_M1WS  8192ull                  // [2][64][4r][128h] f32 = 262144
#define OFF_M2WS  (OFF_M1WS + 262144ull)   // [2][64][4r][128h] f32
#define OFF_SPKW  (OFF_M2WS + 262144ull)   // [2][64][4r][4q] u32 = 8192
#define OFF_FEAT  (OFF_SPKW + 8192ull)     // [256][128] f32 = 131072
#define OFF_AB    (OFF_FEAT + 131072ull)   // a[64], b[64] = 512
#define OFF_PART  (OFF_AB   + 512ull)      // [2304][64][2] f32 = 1179648
#define OFF_MASK  (OFF_PART + 1179648ull)  // [2000][256] u64 = 4096000
#define ZERO_WORDS 133120                  // flags + m1ws + m2ws

// ============================================================
// K0: zero flags + state buffers (every launch, for graph replay)
// ============================================================
__global__ __launch_bounds__(256) void k0_zero(unsigned* ws) {
  int i = blockIdx.x * 256 + threadIdx.x;
  if (i < ZERO_WORDS) ws[i] = 0u;
}

// ============================================================
// K1: conv1d -> per-(b,tile) partial sum/sumsq for BN
// ============================================================
__global__ __launch_bounds__(256) void k1_stats(const float* __restrict__ x,
                                                const float* __restrict__ cw,
                                                float* __restrict__ part) {
  __shared__ float xLds[244 * CIN];
  __shared__ float cwLds[64 * 70];
  __shared__ float red[2][4][64];
  const int b = blockIdx.x, tile = blockIdx.y;
  const int base = tile * 240;
  for (int f = threadIdx.x; f < 244 * CIN; f += 256) {
    int u = f / CIN, ci = f - u * CIN;
    int tp = base + u - 2;
    xLds[f] = (tp >= 0 && tp < TSTEPS) ? x[((size_t)tp * NB + b) * CIN + ci] : 0.0f;
  }
  for (int f = threadIdx.x; f < 64 * 70; f += 256) cwLds[f] = cw[f];
  __syncthreads();

  const int co = threadIdx.x & 63, tq = threadIdx.x >> 6;
  float cwr[70];
#pragma unroll
  for (int s = 0; s < 70; ++s) cwr[s] = cwLds[co * 70 + s];
  float xw[5][CIN];
  const int u0 = tq * 60;
#pragma unroll
  for (int r = 0; r < 4; ++r)
#pragma unroll
    for (int ci = 0; ci < CIN; ++ci) xw[r][ci] = xLds[(u0 + r) * CIN + ci];

  float s1 = 0.0f, s2 = 0.0f;
  const int tbase = base + tq * 60;
  for (int i5 = 0; i5 < 60; i5 += 5) {
#pragma unroll
    for (int s = 0; s < 5; ++s) {
#pragma unroll
      for (int ci = 0; ci < CIN; ++ci)
        xw[(s + 4) % 5][ci] = xLds[(u0 + i5 + s + 4) * CIN + ci];
      float y = 0.0f;
#pragma unroll
      for (int kk = 0; kk < 5; ++kk)
#pragma unroll
        for (int ci = 0; ci < CIN; ++ci)
          y += xw[(s + kk) % 5][ci] * cwr[ci * 5 + kk];
      if (tbase + i5 + s < TSTEPS) { s1 += y; s2 += y * y; }
    }
  }
  red[0][tq][co] = s1; red[1][tq][co] = s2;
  __syncthreads();
  if (threadIdx.x < 64) {
    float a1 = red[0][0][co] + red[0][1][co] + red[0][2][co] + red[0][3][co];
    float a2 = red[1][0][co] + red[1][1][co] + red[1][2][co] + red[1][3][co];
    int blk = tile * NB + b;
    part[blk * 128 + co * 2 + 0] = a1;
    part[blk * 128 + co * 2 + 1] = a2;
  }
}

// K1b: deterministic fixed-order reduction of partials -> a[co], b[co]
__global__ __launch_bounds__(256) void k1b_reduce(const float* __restrict__ gamma,
                           const float* __restrict__ beta,
                           const float* __restrict__ part, float* __restrict__ ab) {
  __shared__ float red[2][4][64];
  const int co = threadIdx.x & 63, pt = threadIdx.x >> 6;
  float s1 = 0.0f, s2 = 0.0f;
  for (int blk = pt * 576; blk < pt * 576 + 576; ++blk) {
    s1 += part[blk * 128 + co * 2 + 0];
    s2 += part[blk * 128 + co * 2 + 1];
  }
  red[0][pt][co] = s1; red[1][pt][co] = s2;
  __syncthreads();
  if (threadIdx.x < 64) {
    float a1 = red[0][0][co] + red[0][1][co] + red[0][2][co] + red[0][3][co];
    float a2 = red[1][0][co] + red[1][1][co] + red[1][2][co] + red[1][3][co];
    const float N = (float)TSTEPS * (float)NB;
    float mu = a1 / N;
    float var = a2 / N - mu * mu;
    float rstd = 1.0f / sqrtf(var + 1e-5f);
    float a = gamma[co] * rstd;
    ab[co] = a;
    ab[64 + co] = beta[co] - mu * a;
  }
}

// ============================================================
// K2: conv1d -> BN -> spike -> pack 64 channel bits into u64 per (t,b)
// ============================================================
__global__ __launch_bounds__(256) void k2_spike(const float* __restrict__ x,
                                                const float* __restrict__ cw,
                                                const float* __restrict__ thrp,
                                                const float* __restrict__ ab,
                                                unsigned long long* __restrict__ masks) {
  __shared__ float xLds[244 * CIN];
  __shared__ float cwLds[64 * 70];
  const int b = blockIdx.x, tile = blockIdx.y;
  const int base = tile * 240;
  for (int f = threadIdx.x; f < 244 * CIN; f += 256) {
    int u = f / CIN, ci = f - u * CIN;
    int tp = base + u - 2;
    xLds[f] = (tp >= 0 && tp < TSTEPS) ? x[((size_t)tp * NB + b) * CIN + ci] : 0.0f;
  }
  for (int f = threadIdx.x; f < 64 * 70; f += 256) cwLds[f] = cw[f];
  __syncthreads();

  const int co = threadIdx.x & 63, tq = threadIdx.x >> 6;
  const float thr = thrp[0];
  const float aC = ab[co], bC = ab[64 + co];
  float cwr[70];
#pragma unroll
  for (int s = 0; s < 70; ++s) cwr[s] = cwLds[co * 70 + s];
  float xw[5][CIN];
  const int u0 = tq * 60;
#pragma unroll
  for (int r = 0; r < 4; ++r)
#pragma unroll
    for (int ci = 0; ci < CIN; ++ci) xw[r][ci] = xLds[(u0 + r) * CIN + ci];

  const int tbase = base + tq * 60;
  for (int i5 = 0; i5 < 60; i5 += 5) {
#pragma unroll
    for (int s = 0; s < 5; ++s) {
#pragma unroll
      for (int ci = 0; ci < CIN; ++ci)
        xw[(s + 4) % 5][ci] = xLds[(u0 + i5 + s + 4) * CIN + ci];
      float y = 0.0f;
#pragma unroll
      for (int kk = 0; kk < 5; ++kk)
#pragma unroll
        for (int ci = 0; ci < CIN; ++ci)
          y += xw[(s + kk) % 5][ci] * cwr[ci * 5 + kk];
      int t = tbase + i5 + s;
      if (t < TSTEPS) {
        float bn = y * aC + bC;
        unsigned long long m = __ballot(bn - thr > 0.0f);  // lane i = channel i
        if (co == 0) masks[(size_t)t * NB + b] = m;
      }
    }
  }
}

// ============================================================
// KP: fused persistent two-layer SLSTM, software-pipelined (L1 step p +
// L2 step p-1 per phase), fence-free flag sync (relaxed-agent atomics).
// Round-6 = validated recombination:
//  - r5 GEMM: 2 gate rows/thread, 8-way k-interleave, flat [k][4r] LDS
//    A layout (0 bank conflicts measured).
//  - r4 GLOBAL state layout [r][h-contig]: coalesced 32-float publish
//    runs (r5's [k][r] layout caused partial-line RMW: WRITE/FETCH blew up).
//  - s_sleep(1) poll restored (r5 busy-poll flooded L3: FETCH 4.9GB).
//  - 80KB dynamic LDS keeps 1 block/CU.
// ============================================================
__global__ __launch_bounds__(512) void kp_fused(char* ws,
    const float* __restrict__ w_ih1, const float* __restrict__ w_hh1,
    const float* __restrict__ b_ih1, const float* __restrict__ b_hh1,
    const float* __restrict__ thr1p,
    const float* __restrict__ w_ih2, const float* __restrict__ w_hh2,
    const float* __restrict__ b_ih2, const float* __restrict__ b_hh2,
    const float* __restrict__ thr2p) {
  extern __shared__ float dynbuf[];        // 80KB requested at launch
  float* A1 = dynbuf;                      // [192 k][4 r]
  float* A2 = dynbuf + 768;                // [256 k][4 r]
  __shared__ float gate1L[128 * 5];        // stride 5 breaks bank pattern
  __shared__ float gate2L[128 * 5];
  __shared__ float biasL1[128], biasL2[128];

  const int tid = threadIdx.x;
  const int bid = blockIdx.x;
  const int g = bid & 63;          // group; peers bid = g+64k
  const int q = bid >> 6;          // h-quarter 0..3
  const int lane = tid & 63, wv = tid >> 6;
  const int u = lane & 7, kq = lane >> 3;  // 8-way k-split, u -> 2 j's
  const int jl0 = wv * 16 + u * 2;         // local gate-row base (0..126)

  unsigned* flags = (unsigned*)(ws + OFF_CNT);   // [(g*4+q)*8], 32B apart
  float* m1ws = (float*)(ws + OFF_M1WS);
  float* m2ws = (float*)(ws + OFF_M2WS);
  unsigned* spkw = (unsigned*)(ws + OFF_SPKW);
  float* feat = (float*)(ws + OFF_FEAT);
  const unsigned long long* masks = (const unsigned long long*)(ws + OFF_MASK);

  // ---- one-time: weights -> registers (k = m*8 + kq interleave) ----
  float wr1[2][24], wr2[2][32];
#pragma unroll
  for (int jj = 0; jj < 2; ++jj) {
    const int j = jl0 + jj;                // 0..127
    const int a = j >> 5, hl = j & 31;
    const int grow = a * 128 + q * 32 + hl;
#pragma unroll
    for (int m = 0; m < 24; ++m) {
      int k = m * 8 + kq;
      wr1[jj][m] = (k < 64) ? w_ih1[grow * 64 + k] : w_hh1[grow * 128 + (k - 64)];
    }
#pragma unroll
    for (int m = 0; m < 32; ++m) {
      int k = m * 8 + kq;
      wr2[jj][m] = (k < 128) ? w_ih2[grow * 128 + k] : w_hh2[grow * 128 + (k - 128)];
    }
  }
  if (tid < 128) {
    int aa = tid >> 5, h2 = tid & 31;
    int gr = aa * 128 + q * 32 + h2;
    biasL1[tid] = b_ih1[gr] + b_hh1[gr];
    biasL2[tid] = b_ih2[gr] + b_hh2[gr];
  }
  const float thr1 = thr1p[0], thr2 = thr2p[0];
  const int cr = tid >> 5, chl = tid & 31;   // cell mapping for tid<128
  float syn1 = 0.0f, mem1 = 0.0f, syn2 = 0.0f, mem2 = 0.0f, facc = 0.0f;
  __syncthreads();

  // conv-spike mask for step 0 (row = tid&3)
  unsigned long long mrow = masks[(size_t)0 * NB + g * RG + (tid & 3)];

  for (int p = 0; p <= TSTEPS; ++p) {
    const int rb1 = (p + 1) & 1;   // parity of p-1
    const int wb = p & 1;          // parity of p

    // ---- single load burst (global layout [r][h]; LDS layout [k][r]) ----
    if (tid < 256) {               // A1 k<64: conv spike bits (k=tid>>2,e=tid&3)
      A1[tid] = (float)((mrow >> (tid >> 2)) & 1ull);
    }
    {                              // A1 k in [64,192): m1(p-1); k-64=tid>>2, r=tid&3
      float v = __hip_atomic_load(
          &m1ws[(size_t)(rb1 * 64 + g) * 512 + (tid & 3) * 128 + (tid >> 2)],
          __ATOMIC_RELAXED, __HIP_MEMORY_SCOPE_AGENT);
      A1[256 + tid] = v;
    }
    {                              // A2 k<128: spk1(p-1) bits
      int k = tid >> 2, e = tid & 3;
      unsigned uu = __hip_atomic_load(&spkw[((rb1 * 64 + g) * 4 + e) * 4 + (k >> 5)],
                                      __ATOMIC_RELAXED, __HIP_MEMORY_SCOPE_AGENT);
      A2[tid] = (float)((uu >> (k & 31)) & 1u);
    }
    {                              // A2 k in [128,256): m2(p-2); k-128=tid>>2, r=tid&3
      float v = __hip_atomic_load(
          &m2ws[(size_t)(wb * 64 + g) * 512 + (tid & 3) * 128 + (tid >> 2)],
          __ATOMIC_RELAXED, __HIP_MEMORY_SCOPE_AGENT);
      A2[512 + tid] = v;
    }
    if (p + 1 < TSTEPS) mrow = masks[(size_t)(p + 1) * NB + g * RG + (tid & 3)];
    __syncthreads();

    // ---- GEMM1: K=192, k = m*8+kq, 2 j rows per thread ----
    {
      float ac[2][4];
#pragma unroll
      for (int jj = 0; jj < 2; ++jj)
#pragma unroll
        for (int r = 0; r < 4; ++r) ac[jj][r] = 0.0f;
      const float4* A1v = (const float4*)A1;
#pragma unroll
      for (int m = 0; m < 24; ++m) {
        float4 av = A1v[m * 8 + kq];
        float w0 = wr1[0][m], w1 = wr1[1][m];
        ac[0][0] += w0 * av.x; ac[0][1] += w0 * av.y;
        ac[0][2] += w0 * av.z; ac[0][3] += w0 * av.w;
        ac[1][0] += w1 * av.x; ac[1][1] += w1 * av.y;
        ac[1][2] += w1 * av.z; ac[1][3] += w1 * av.w;
      }
#pragma unroll
      for (int jj = 0; jj < 2; ++jj)
#pragma unroll
        for (int r = 0; r < 4; ++r) {
          float v = ac[jj][r];
          v += __shfl_xor(v, 8); v += __shfl_xor(v, 16); v += __shfl_xor(v, 32);
          ac[jj][r] = v;
        }
      if (kq == 0) {
#pragma unroll
        for (int jj = 0; jj < 2; ++jj)
#pragma unroll
          for (int r = 0; r < 4; ++r)
            gate1L[(jl0 + jj) * 5 + r] = ac[jj][r];
      }
    }
    // ---- GEMM2: K=256 ----
    {
      float ac[2][4];
#pragma unroll
      for (int jj = 0; jj < 2; ++jj)
#pragma unroll
        for (int r = 0; r < 4; ++r) ac[jj][r] = 0.0f;
      const float4* A2v = (const float4*)A2;
#pragma unroll
      for (int m = 0; m < 32; ++m) {
        float4 av = A2v[m * 8 + kq];
        float w0 = wr2[0][m], w1 = wr2[1][m];
        ac[0][0] += w0 * av.x; ac[0][1] += w0 * av.y;
        ac[0][2] += w0 * av.z; ac[0][3] += w0 * av.w;
        ac[1][0] += w1 * av.x; ac[1][1] += w1 * av.y;
        ac[1][2] += w1 * av.z; ac[1][3] += w1 * av.w;
      }
#pragma unroll
      for (int jj = 0; jj < 2; ++jj)
#pragma unroll
        for (int r = 0; r < 4; ++r) {
          float v = ac[jj][r];
          v += __shfl_xor(v, 8); v += __shfl_xor(v, 16); v += __shfl_xor(v, 32);
          ac[jj][r] = v;
        }
      if (kq == 0) {
#pragma unroll
        for (int jj = 0; jj < 2; ++jj)
#pragma unroll
          for (int r = 0; r < 4; ++r)
            gate2L[(jl0 + jj) * 5 + r] = ac[jj][r];
      }
    }
    __syncthreads();

    // ---- cell1 (step p) + publish m1(p), spk1(p) ----
    if (tid < 128 && p < TSTEPS) {
      float g0 = biasL1[chl]       + gate1L[(chl) * 5 + cr];
      float g1 = biasL1[32 + chl]  + gate1L[(32 + chl) * 5 + cr];
      float g2 = biasL1[64 + chl]  + gate1L[(64 + chl) * 5 + cr];
      float g3 = biasL1[96 + chl]  + gate1L[(96 + chl) * 5 + cr];
      float rst = (mem1 - thr1 > 0.0f) ? thr1 : 0.0f;
      float ig = 1.0f / (1.0f + expf(-g0));
      float fg = 1.0f / (1.0f + expf(-g1));
      float gg = tanhf(g2);
      float og = 1.0f / (1.0f + expf(-g3));
      float cn = fg * syn1 + ig * gg;
      float mn = og * tanhf(cn) - rst;
      syn1 = cn; mem1 = mn;
      __hip_atomic_store(
          &m1ws[(size_t)(wb * 64 + g) * 512 + cr * 128 + (q * 32 + chl)],
          mn, __ATOMIC_RELAXED, __HIP_MEMORY_SCOPE_AGENT);
      unsigned long long bal = __ballot(mn - thr1 > 0.0f);
      if (lane == 0)
        __hip_atomic_store(&spkw[((wb * 64 + g) * 4 + (wv * 2 + 0)) * 4 + q],
                           (unsigned)(bal & 0xffffffffull),
                           __ATOMIC_RELAXED, __HIP_MEMORY_SCOPE_AGENT);
      if (lane == 32)
        __hip_atomic_store(&spkw[((wb * 64 + g) * 4 + (wv * 2 + 1)) * 4 + q],
                           (unsigned)(bal >> 32),
                           __ATOMIC_RELAXED, __HIP_MEMORY_SCOPE_AGENT);
    }
    // ---- cell2 (step p-1) + publish m2(p-1) + feature accum ----
    if (tid < 128 && p >= 1) {
      float g0 = biasL2[chl]       + gate2L[(chl) * 5 + cr];
      float g1 = biasL2[32 + chl]  + gate2L[(32 + chl) * 5 + cr];
      float g2 = biasL2[64 + chl]  + gate2L[(64 + chl) * 5 + cr];
      float g3 = biasL2[96 + chl]  + gate2L[(96 + chl) * 5 + cr];
      float rst = (mem2 - thr2 > 0.0f) ? thr2 : 0.0f;
      float ig = 1.0f / (1.0f + expf(-g0));
      float fg = 1.0f / (1.0f + expf(-g1));
      float gg = tanhf(g2);
      float og = 1.0f / (1.0f + expf(-g3));
      float cn = fg * syn2 + ig * gg;
      float mn = og * tanhf(cn) - rst;
      syn2 = cn; mem2 = mn;
      __hip_atomic_store(
          &m2ws[(size_t)(rb1 * 64 + g) * 512 + cr * 128 + (q * 32 + chl)],
          mn, __ATOMIC_RELAXED, __HIP_MEMORY_SCOPE_AGENT);
      facc += mn;
    }
    __syncthreads();  // drains vmcnt(0): all publishes ACKed at coherence point

    // ---- ONE distributed-flag barrier per phase (fence-free, no RMW) ----
    if (p < TSTEPS) {
      if (tid == 0)
        __hip_atomic_store(&flags[(g * 4 + q) * 8], (unsigned)(p + 1),
                           __ATOMIC_RELAXED, __HIP_MEMORY_SCOPE_AGENT);
      if (tid < 4) {
        while (__hip_atomic_load(&flags[(g * 4 + tid) * 8],
                                 __ATOMIC_RELAXED, __HIP_MEMORY_SCOPE_AGENT)
               < (unsigned)(p + 1))
          __builtin_amdgcn_s_sleep(1);
      }
      __syncthreads();
    }
  }

  if (tid < 128)
    feat[(g * RG + cr) * 128 + q * 32 + chl] = facc * (1.0f / (float)TSTEPS);
}

// ============================================================
// K3: head — gesture + (binary) domain_hidden -> domain
// ============================================================
__global__ __launch_bounds__(128) void k3_head(const float* __restrict__ feat,
    const float* __restrict__ gw, const float* __restrict__ gb,
    const float* __restrict__ d1w, const float* __restrict__ d1b,
    const float* __restrict__ thrdp,
    const float* __restrict__ d2w, const float* __restrict__ d2b,
    float* __restrict__ out) {
  __shared__ float fL[128];
  __shared__ float dh[64];
  const int b = blockIdx.x, t = threadIdx.x;
  fL[t] = feat[b * 128 + t];
  __syncthreads();
  if (t < 64) {
    float s = d1b[t];
    for (int k = 0; k < 128; ++k) s += d1w[t * 128 + k] * fL[k];
    dh[t] = (s - thrdp[0] > 0.0f) ? 1.0f : 0.0f;
  }
  __syncthreads();
  if (t < 8) {
    float s = gb[t];
    for (int k = 0; k < 128; ++k) s += gw[t * 128 + k] * fL[k];
    out[b * 8 + t] = s;
  }
  if (t >= 64 && t < 74) {
    const int o = t - 64;
    float s = d2b[o];
    for (int k = 0; k < 64; ++k) s += d2w[o * 64 + k] * dh[k];
    out[2048 + b * 10 + o] = s;
  }
}

// ============================================================
extern "C" void kernel_launch(void* const* d_in, const int* in_sizes, int n_in,
                              void* d_out, int out_size, void* d_ws, size_t ws_size,
                              hipStream_t stream) {
  const float* x      = (const float*)d_in[0];
  const float* conv_w = (const float*)d_in[1];
  const float* bn_g   = (const float*)d_in[2];
  const float* bn_b   = (const float*)d_in[3];
  const float* thrl1  = (const float*)d_in[4];
  const float* w_ih1  = (const float*)d_in[5];
  const float* w_hh1  = (const float*)d_in[6];
  const float* b_ih1  = (const float*)d_in[7];
  const float* b_hh1  = (const float*)d_in[8];
  const float* thr1   = (const float*)d_in[9];
  const float* w_ih2  = (const float*)d_in[10];
  const float* w_hh2  = (const float*)d_in[11];
  const float* b_ih2  = (const float*)d_in[12];
  const float* b_hh2  = (const float*)d_in[13];
  const float* thr2   = (const float*)d_in[14];
  const float* fc_g_w = (const float*)d_in[15];
  const float* fc_g_b = (const float*)d_in[16];
  const float* fc_d1w = (const float*)d_in[17];
  const float* fc_d1b = (const float*)d_in[18];
  const float* thrdom = (const float*)d_in[19];
  const float* fc_d2w = (const float*)d_in[20];
  const float* fc_d2b = (const float*)d_in[21];
  float* out = (float*)d_out;
  char* ws = (char*)d_ws;

  k0_zero<<<(ZERO_WORDS + 255) / 256, 256, 0, stream>>>((unsigned*)ws);
  k1_stats<<<dim3(NB, 9), 256, 0, stream>>>(x, conv_w, (float*)(ws + OFF_PART));
  k1b_reduce<<<1, 256, 0, stream>>>(bn_g, bn_b, (const float*)(ws + OFF_PART),
                                    (float*)(ws + OFF_AB));
  k2_spike<<<dim3(NB, 9), 256, 0, stream>>>(x, conv_w, thrl1,
                                            (const float*)(ws + OFF_AB),
                                            (unsigned long long*)(ws + OFF_MASK));
  // 80KB dynamic LDS: forces exactly 1 persistent block per CU
  kp_fused<<<NGRP * BPG, 512, 81920, stream>>>(ws, w_ih1, w_hh1, b_ih1, b_hh1, thr1,
                                               w_ih2, w_hh2, b_ih2, b_hh2, thr2);
  k3_head<<<NB, 128, 0, stream>>>((const float*)(ws + OFF_FEAT), fc_g_w, fc_g_b,
                                  fc_d1w, fc_d1b, thrdom, fc_d2w, fc_d2b, out);
}

// Round 7
// 23196.523 us; speedup vs baseline: 1.0496x; 1.0058x over previous
//
#include <hip/hip_runtime.h>
#include <cstdint>
#include <cstddef>

// ---------------- problem constants ----------------
#define TSTEPS 2000
#define NB     256      // batch
#define HID    128
#define CIN    14
#define NGRP   64       // row groups
#define RG     4        // rows per group
#define BPG    4        // blocks per group (h-quarters, each does L1+L2)

// ---------------- workspace layout (bytes) ----------------
#define OFF_CNT   0ull                     // 256 flags * 32B = 8192
#define OFF_M1WS  8192ull                  // [2][64][4r][128h] f32 = 262144
#define OFF_M2WS  (OFF_M1WS + 262144ull)   // [2][64][4r][128h] f32
#define OFF_SPKW  (OFF_M2WS + 262144ull)   // [2][64][4r][4q] u32 = 8192
#define OFF_FEAT  (OFF_SPKW + 8192ull)     // [256][128] f32 = 131072
#define OFF_AB    (OFF_FEAT + 131072ull)   // a[64], b[64] = 512
#define OFF_PART  (OFF_AB   + 512ull)      // [2304][64][2] f32 = 1179648
#define OFF_MASK  (OFF_PART + 1179648ull)  // [2000][256] u64 = 4096000
#define ZERO_WORDS 133120                  // flags + m1ws + m2ws

// ============================================================
// K0: zero flags + state buffers (every launch, for graph replay)
// ============================================================
__global__ __launch_bounds__(256) void k0_zero(unsigned* ws) {
  int i = blockIdx.x * 256 + threadIdx.x;
  if (i < ZERO_WORDS) ws[i] = 0u;
}

// ============================================================
// K1: conv1d -> per-(b,tile) partial sum/sumsq for BN
// ============================================================
__global__ __launch_bounds__(256) void k1_stats(const float* __restrict__ x,
                                                const float* __restrict__ cw,
                                                float* __restrict__ part) {
  __shared__ float xLds[244 * CIN];
  __shared__ float cwLds[64 * 70];
  __shared__ float red[2][4][64];
  const int b = blockIdx.x, tile = blockIdx.y;
  const int base = tile * 240;
  for (int f = threadIdx.x; f < 244 * CIN; f += 256) {
    int u = f / CIN, ci = f - u * CIN;
    int tp = base + u - 2;
    xLds[f] = (tp >= 0 && tp < TSTEPS) ? x[((size_t)tp * NB + b) * CIN + ci] : 0.0f;
  }
  for (int f = threadIdx.x; f < 64 * 70; f += 256) cwLds[f] = cw[f];
  __syncthreads();

  const int co = threadIdx.x & 63, tq = threadIdx.x >> 6;
  float cwr[70];
#pragma unroll
  for (int s = 0; s < 70; ++s) cwr[s] = cwLds[co * 70 + s];
  float xw[5][CIN];
  const int u0 = tq * 60;
#pragma unroll
  for (int r = 0; r < 4; ++r)
#pragma unroll
    for (int ci = 0; ci < CIN; ++ci) xw[r][ci] = xLds[(u0 + r) * CIN + ci];

  float s1 = 0.0f, s2 = 0.0f;
  const int tbase = base + tq * 60;
  for (int i5 = 0; i5 < 60; i5 += 5) {
#pragma unroll
    for (int s = 0; s < 5; ++s) {
#pragma unroll
      for (int ci = 0; ci < CIN; ++ci)
        xw[(s + 4) % 5][ci] = xLds[(u0 + i5 + s + 4) * CIN + ci];
      float y = 0.0f;
#pragma unroll
      for (int kk = 0; kk < 5; ++kk)
#pragma unroll
        for (int ci = 0; ci < CIN; ++ci)
          y += xw[(s + kk) % 5][ci] * cwr[ci * 5 + kk];
      if (tbase + i5 + s < TSTEPS) { s1 += y; s2 += y * y; }
    }
  }
  red[0][tq][co] = s1; red[1][tq][co] = s2;
  __syncthreads();
  if (threadIdx.x < 64) {
    float a1 = red[0][0][co] + red[0][1][co] + red[0][2][co] + red[0][3][co];
    float a2 = red[1][0][co] + red[1][1][co] + red[1][2][co] + red[1][3][co];
    int blk = tile * NB + b;
    part[blk * 128 + co * 2 + 0] = a1;
    part[blk * 128 + co * 2 + 1] = a2;
  }
}

// K1b: deterministic fixed-order reduction of partials -> a[co], b[co]
__global__ __launch_bounds__(256) void k1b_reduce(const float* __restrict__ gamma,
                           const float* __restrict__ beta,
                           const float* __restrict__ part, float* __restrict__ ab) {
  __shared__ float red[2][4][64];
  const int co = threadIdx.x & 63, pt = threadIdx.x >> 6;
  float s1 = 0.0f, s2 = 0.0f;
  for (int blk = pt * 576; blk < pt * 576 + 576; ++blk) {
    s1 += part[blk * 128 + co * 2 + 0];
    s2 += part[blk * 128 + co * 2 + 1];
  }
  red[0][pt][co] = s1; red[1][pt][co] = s2;
  __syncthreads();
  if (threadIdx.x < 64) {
    float a1 = red[0][0][co] + red[0][1][co] + red[0][2][co] + red[0][3][co];
    float a2 = red[1][0][co] + red[1][1][co] + red[1][2][co] + red[1][3][co];
    const float N = (float)TSTEPS * (float)NB;
    float mu = a1 / N;
    float var = a2 / N - mu * mu;
    float rstd = 1.0f / sqrtf(var + 1e-5f);
    float a = gamma[co] * rstd;
    ab[co] = a;
    ab[64 + co] = beta[co] - mu * a;
  }
}

// ============================================================
// K2: conv1d -> BN -> spike -> pack 64 channel bits into u64 per (t,b)
// ============================================================
__global__ __launch_bounds__(256) void k2_spike(const float* __restrict__ x,
                                                const float* __restrict__ cw,
                                                const float* __restrict__ thrp,
                                                const float* __restrict__ ab,
                                                unsigned long long* __restrict__ masks) {
  __shared__ float xLds[244 * CIN];
  __shared__ float cwLds[64 * 70];
  const int b = blockIdx.x, tile = blockIdx.y;
  const int base = tile * 240;
  for (int f = threadIdx.x; f < 244 * CIN; f += 256) {
    int u = f / CIN, ci = f - u * CIN;
    int tp = base + u - 2;
    xLds[f] = (tp >= 0 && tp < TSTEPS) ? x[((size_t)tp * NB + b) * CIN + ci] : 0.0f;
  }
  for (int f = threadIdx.x; f < 64 * 70; f += 256) cwLds[f] = cw[f];
  __syncthreads();

  const int co = threadIdx.x & 63, tq = threadIdx.x >> 6;
  const float thr = thrp[0];
  const float aC = ab[co], bC = ab[64 + co];
  float cwr[70];
#pragma unroll
  for (int s = 0; s < 70; ++s) cwr[s] = cwLds[co * 70 + s];
  float xw[5][CIN];
  const int u0 = tq * 60;
#pragma unroll
  for (int r = 0; r < 4; ++r)
#pragma unroll
    for (int ci = 0; ci < CIN; ++ci) xw[r][ci] = xLds[(u0 + r) * CIN + ci];

  const int tbase = base + tq * 60;
  for (int i5 = 0; i5 < 60; i5 += 5) {
#pragma unroll
    for (int s = 0; s < 5; ++s) {
#pragma unroll
      for (int ci = 0; ci < CIN; ++ci)
        xw[(s + 4) % 5][ci] = xLds[(u0 + i5 + s + 4) * CIN + ci];
      float y = 0.0f;
#pragma unroll
      for (int kk = 0; kk < 5; ++kk)
#pragma unroll
        for (int ci = 0; ci < CIN; ++ci)
          y += xw[(s + kk) % 5][ci] * cwr[ci * 5 + kk];
      int t = tbase + i5 + s;
      if (t < TSTEPS) {
        float bn = y * aC + bC;
        unsigned long long m = __ballot(bn - thr > 0.0f);  // lane i = channel i
        if (co == 0) masks[(size_t)t * NB + b] = m;
      }
    }
  }
}

// ============================================================
// KP: fused persistent two-layer SLSTM, software-pipelined (L1 step p +
// L2 step p-1 per phase), fence-free flag sync (relaxed-agent atomics).
// Round-7: BARRIER HIDDEN UNDER GEMM2.
//   stage -> sync -> GEMM1 -> sync -> cell1+publish(m1,spk1) ->
//   sync(drain) -> flag(p+1) -> GEMM2 -> sync -> cell2+publish(m2) ->
//   poll(peers' flags, set ~one GEMM2 ago -> usually immediate) -> sync
// Flag(p+1) only guards m1(p), spk1(p), m2(p-1): all drained by the sync
// preceding it (m2(p-1) published a full phase earlier). Static 13KB LDS
// restores 2 blocks/CU (r4-validated; 1-block clamp didn't fix the slow
// mode and hurt latency hiding). Arithmetic bit-identical to r6.
// ============================================================
__global__ __launch_bounds__(512) void kp_fused(char* ws,
    const float* __restrict__ w_ih1, const float* __restrict__ w_hh1,
    const float* __restrict__ b_ih1, const float* __restrict__ b_hh1,
    const float* __restrict__ thr1p,
    const float* __restrict__ w_ih2, const float* __restrict__ w_hh2,
    const float* __restrict__ b_ih2, const float* __restrict__ b_hh2,
    const float* __restrict__ thr2p) {
  __shared__ __align__(16) float A1[192 * 4];   // [k][4 r]
  __shared__ __align__(16) float A2[256 * 4];
  __shared__ float gate1L[128 * 5];             // stride 5 breaks bank pattern
  __shared__ float gate2L[128 * 5];
  __shared__ float biasL1[128], biasL2[128];

  const int tid = threadIdx.x;
  const int bid = blockIdx.x;
  const int g = bid & 63;          // group; peers bid = g+64k
  const int q = bid >> 6;          // h-quarter 0..3
  const int lane = tid & 63, wv = tid >> 6;
  const int u = lane & 7, kq = lane >> 3;  // 8-way k-split, u -> 2 j's
  const int jl0 = wv * 16 + u * 2;         // local gate-row base (0..126)

  unsigned* flags = (unsigned*)(ws + OFF_CNT);   // [(g*4+q)*8], 32B apart
  float* m1ws = (float*)(ws + OFF_M1WS);
  float* m2ws = (float*)(ws + OFF_M2WS);
  unsigned* spkw = (unsigned*)(ws + OFF_SPKW);
  float* feat = (float*)(ws + OFF_FEAT);
  const unsigned long long* masks = (const unsigned long long*)(ws + OFF_MASK);

  // ---- one-time: weights -> registers (k = m*8 + kq interleave) ----
  float wr1[2][24], wr2[2][32];
#pragma unroll
  for (int jj = 0; jj < 2; ++jj) {
    const int j = jl0 + jj;                // 0..127
    const int a = j >> 5, hl = j & 31;
    const int grow = a * 128 + q * 32 + hl;
#pragma unroll
    for (int m = 0; m < 24; ++m) {
      int k = m * 8 + kq;
      wr1[jj][m] = (k < 64) ? w_ih1[grow * 64 + k] : w_hh1[grow * 128 + (k - 64)];
    }
#pragma unroll
    for (int m = 0; m < 32; ++m) {
      int k = m * 8 + kq;
      wr2[jj][m] = (k < 128) ? w_ih2[grow * 128 + k] : w_hh2[grow * 128 + (k - 128)];
    }
  }
  if (tid < 128) {
    int aa = tid >> 5, h2 = tid & 31;
    int gr = aa * 128 + q * 32 + h2;
    biasL1[tid] = b_ih1[gr] + b_hh1[gr];
    biasL2[tid] = b_ih2[gr] + b_hh2[gr];
  }
  const float thr1 = thr1p[0], thr2 = thr2p[0];
  const int cr = tid >> 5, chl = tid & 31;   // cell mapping for tid<128
  float syn1 = 0.0f, mem1 = 0.0f, syn2 = 0.0f, mem2 = 0.0f, facc = 0.0f;
  __syncthreads();

  // conv-spike mask for step 0 (row = tid&3)
  unsigned long long mrow = masks[(size_t)0 * NB + g * RG + (tid & 3)];

  for (int p = 0; p <= TSTEPS; ++p) {
    const int rb1 = (p + 1) & 1;   // parity of p-1
    const int wb = p & 1;          // parity of p

    // ---- stage A1 (L1 step p) and A2 (L2 step p-1) ----
    if (tid < 256) {               // A1 k<64: conv spike bits
      A1[tid] = (float)((mrow >> (tid >> 2)) & 1ull);
    }
    {                              // A1 k in [64,192): m1(p-1)
      float v = __hip_atomic_load(
          &m1ws[(size_t)(rb1 * 64 + g) * 512 + (tid & 3) * 128 + (tid >> 2)],
          __ATOMIC_RELAXED, __HIP_MEMORY_SCOPE_AGENT);
      A1[256 + tid] = v;
    }
    {                              // A2 k<128: spk1(p-1) bits
      int k = tid >> 2, e = tid & 3;
      unsigned uu = __hip_atomic_load(&spkw[((rb1 * 64 + g) * 4 + e) * 4 + (k >> 5)],
                                      __ATOMIC_RELAXED, __HIP_MEMORY_SCOPE_AGENT);
      A2[tid] = (float)((uu >> (k & 31)) & 1u);
    }
    {                              // A2 k in [128,256): m2(p-2)
      float v = __hip_atomic_load(
          &m2ws[(size_t)(wb * 64 + g) * 512 + (tid & 3) * 128 + (tid >> 2)],
          __ATOMIC_RELAXED, __HIP_MEMORY_SCOPE_AGENT);
      A2[512 + tid] = v;
    }
    if (p + 1 < TSTEPS) mrow = masks[(size_t)(p + 1) * NB + g * RG + (tid & 3)];
    __syncthreads();   // sync1: staging visible

    // ---- GEMM1: K=192, k = m*8+kq, 2 j rows per thread ----
    {
      float ac[2][4];
#pragma unroll
      for (int jj = 0; jj < 2; ++jj)
#pragma unroll
        for (int r = 0; r < 4; ++r) ac[jj][r] = 0.0f;
      const float4* A1v = (const float4*)A1;
#pragma unroll
      for (int m = 0; m < 24; ++m) {
        float4 av = A1v[m * 8 + kq];
        float w0 = wr1[0][m], w1 = wr1[1][m];
        ac[0][0] += w0 * av.x; ac[0][1] += w0 * av.y;
        ac[0][2] += w0 * av.z; ac[0][3] += w0 * av.w;
        ac[1][0] += w1 * av.x; ac[1][1] += w1 * av.y;
        ac[1][2] += w1 * av.z; ac[1][3] += w1 * av.w;
      }
#pragma unroll
      for (int jj = 0; jj < 2; ++jj)
#pragma unroll
        for (int r = 0; r < 4; ++r) {
          float v = ac[jj][r];
          v += __shfl_xor(v, 8); v += __shfl_xor(v, 16); v += __shfl_xor(v, 32);
          ac[jj][r] = v;
        }
      if (kq == 0) {
#pragma unroll
        for (int jj = 0; jj < 2; ++jj)
#pragma unroll
          for (int r = 0; r < 4; ++r)
            gate1L[(jl0 + jj) * 5 + r] = ac[jj][r];
      }
    }
    __syncthreads();   // sync2: gate1L visible

    // ---- cell1 (step p) + publish m1(p), spk1(p) ----
    if (tid < 128 && p < TSTEPS) {
      float g0 = biasL1[chl]       + gate1L[(chl) * 5 + cr];
      float g1 = biasL1[32 + chl]  + gate1L[(32 + chl) * 5 + cr];
      float g2 = biasL1[64 + chl]  + gate1L[(64 + chl) * 5 + cr];
      float g3 = biasL1[96 + chl]  + gate1L[(96 + chl) * 5 + cr];
      float rst = (mem1 - thr1 > 0.0f) ? thr1 : 0.0f;
      float ig = 1.0f / (1.0f + expf(-g0));
      float fg = 1.0f / (1.0f + expf(-g1));
      float gg = tanhf(g2);
      float og = 1.0f / (1.0f + expf(-g3));
      float cn = fg * syn1 + ig * gg;
      float mn = og * tanhf(cn) - rst;
      syn1 = cn; mem1 = mn;
      __hip_atomic_store(
          &m1ws[(size_t)(wb * 64 + g) * 512 + cr * 128 + (q * 32 + chl)],
          mn, __ATOMIC_RELAXED, __HIP_MEMORY_SCOPE_AGENT);
      unsigned long long bal = __ballot(mn - thr1 > 0.0f);
      if (lane == 0)
        __hip_atomic_store(&spkw[((wb * 64 + g) * 4 + (wv * 2 + 0)) * 4 + q],
                           (unsigned)(bal & 0xffffffffull),
                           __ATOMIC_RELAXED, __HIP_MEMORY_SCOPE_AGENT);
      if (lane == 32)
        __hip_atomic_store(&spkw[((wb * 64 + g) * 4 + (wv * 2 + 1)) * 4 + q],
                           (unsigned)(bal >> 32),
                           __ATOMIC_RELAXED, __HIP_MEMORY_SCOPE_AGENT);
    }
    __syncthreads();   // sync3: drains vmcnt -> m1(p), spk1(p), m2(p-1) ACKed

    // ---- flag release (fire-and-forget) -> peers may stage phase p+1 ----
    if (p < TSTEPS && tid == 0) {
      __hip_atomic_store(&flags[(g * 4 + q) * 8], (unsigned)(p + 1),
                         __ATOMIC_RELAXED, __HIP_MEMORY_SCOPE_AGENT);
      __builtin_amdgcn_sched_barrier(0);  // don't sink the store past GEMM2
    }

    // ---- GEMM2: K=256 (overlaps peers' polling) ----
    {
      float ac[2][4];
#pragma unroll
      for (int jj = 0; jj < 2; ++jj)
#pragma unroll
        for (int r = 0; r < 4; ++r) ac[jj][r] = 0.0f;
      const float4* A2v = (const float4*)A2;
#pragma unroll
      for (int m = 0; m < 32; ++m) {
        float4 av = A2v[m * 8 + kq];
        float w0 = wr2[0][m], w1 = wr2[1][m];
        ac[0][0] += w0 * av.x; ac[0][1] += w0 * av.y;
        ac[0][2] += w0 * av.z; ac[0][3] += w0 * av.w;
        ac[1][0] += w1 * av.x; ac[1][1] += w1 * av.y;
        ac[1][2] += w1 * av.z; ac[1][3] += w1 * av.w;
      }
#pragma unroll
      for (int jj = 0; jj < 2; ++jj)
#pragma unroll
        for (int r = 0; r < 4; ++r) {
          float v = ac[jj][r];
          v += __shfl_xor(v, 8); v += __shfl_xor(v, 16); v += __shfl_xor(v, 32);
          ac[jj][r] = v;
        }
      if (kq == 0) {
#pragma unroll
        for (int jj = 0; jj < 2; ++jj)
#pragma unroll
          for (int r = 0; r < 4; ++r)
            gate2L[(jl0 + jj) * 5 + r] = ac[jj][r];
      }
    }
    __syncthreads();   // sync4: gate2L visible

    // ---- cell2 (step p-1) + publish m2(p-1) + feature accum ----
    if (tid < 128 && p >= 1) {
      float g0 = biasL2[chl]       + gate2L[(chl) * 5 + cr];
      float g1 = biasL2[32 + chl]  + gate2L[(32 + chl) * 5 + cr];
      float g2 = biasL2[64 + chl]  + gate2L[(64 + chl) * 5 + cr];
      float g3 = biasL2[96 + chl]  + gate2L[(96 + chl) * 5 + cr];
      float rst = (mem2 - thr2 > 0.0f) ? thr2 : 0.0f;
      float ig = 1.0f / (1.0f + expf(-g0));
      float fg = 1.0f / (1.0f + expf(-g1));
      float gg = tanhf(g2);
      float og = 1.0f / (1.0f + expf(-g3));
      float cn = fg * syn2 + ig * gg;
      float mn = og * tanhf(cn) - rst;
      syn2 = cn; mem2 = mn;
      __hip_atomic_store(
          &m2ws[(size_t)(rb1 * 64 + g) * 512 + cr * 128 + (q * 32 + chl)],
          mn, __ATOMIC_RELAXED, __HIP_MEMORY_SCOPE_AGENT);
      facc += mn;
    }

    // ---- poll peers' flags (set ~one GEMM2 ago -> usually immediate) ----
    if (p < TSTEPS && tid < 4) {
      while (__hip_atomic_load(&flags[(g * 4 + tid) * 8],
                               __ATOMIC_RELAXED, __HIP_MEMORY_SCOPE_AGENT)
             < (unsigned)(p + 1))
        __builtin_amdgcn_s_sleep(1);
    }
    __syncthreads();   // sync5: all threads saw the barrier; A1/A2 reusable
  }

  if (tid < 128)
    feat[(g * RG + cr) * 128 + q * 32 + chl] = facc * (1.0f / (float)TSTEPS);
}

// ============================================================
// K3: head — gesture + (binary) domain_hidden -> domain
// ============================================================
__global__ __launch_bounds__(128) void k3_head(const float* __restrict__ feat,
    const float* __restrict__ gw, const float* __restrict__ gb,
    const float* __restrict__ d1w, const float* __restrict__ d1b,
    const float* __restrict__ thrdp,
    const float* __restrict__ d2w, const float* __restrict__ d2b,
    float* __restrict__ out) {
  __shared__ float fL[128];
  __shared__ float dh[64];
  const int b = blockIdx.x, t = threadIdx.x;
  fL[t] = feat[b * 128 + t];
  __syncthreads();
  if (t < 64) {
    float s = d1b[t];
    for (int k = 0; k < 128; ++k) s += d1w[t * 128 + k] * fL[k];
    dh[t] = (s - thrdp[0] > 0.0f) ? 1.0f : 0.0f;
  }
  __syncthreads();
  if (t < 8) {
    float s = gb[t];
    for (int k = 0; k < 128; ++k) s += gw[t * 128 + k] * fL[k];
    out[b * 8 + t] = s;
  }
  if (t >= 64 && t < 74) {
    const int o = t - 64;
    float s = d2b[o];
    for (int k = 0; k < 64; ++k) s += d2w[o * 64 + k] * dh[k];
    out[2048 + b * 10 + o] = s;
  }
}

// ============================================================
extern "C" void kernel_launch(void* const* d_in, const int* in_sizes, int n_in,
                              void* d_out, int out_size, void* d_ws, size_t ws_size,
                              hipStream_t stream) {
  const float* x      = (const float*)d_in[0];
  const float* conv_w = (const float*)d_in[1];
  const float* bn_g   = (const float*)d_in[2];
  const float* bn_b   = (const float*)d_in[3];
  const float* thrl1  = (const float*)d_in[4];
  const float* w_ih1  = (const float*)d_in[5];
  const float* w_hh1  = (const float*)d_in[6];
  const float* b_ih1  = (const float*)d_in[7];
  const float* b_hh1  = (const float*)d_in[8];
  const float* thr1   = (const float*)d_in[9];
  const float* w_ih2  = (const float*)d_in[10];
  const float* w_hh2  = (const float*)d_in[11];
  const float* b_ih2  = (const float*)d_in[12];
  const float* b_hh2  = (const float*)d_in[13];
  const float* thr2   = (const float*)d_in[14];
  const float* fc_g_w = (const float*)d_in[15];
  const float* fc_g_b = (const float*)d_in[16];
  const float* fc_d1w = (const float*)d_in[17];
  const float* fc_d1b = (const float*)d_in[18];
  const float* thrdom = (const float*)d_in[19];
  const float* fc_d2w = (const float*)d_in[20];
  const float* fc_d2b = (const float*)d_in[21];
  float* out = (float*)d_out;
  char* ws = (char*)d_ws;

  k0_zero<<<(ZERO_WORDS + 255) / 256, 256, 0, stream>>>((unsigned*)ws);
  k1_stats<<<dim3(NB, 9), 256, 0, stream>>>(x, conv_w, (float*)(ws + OFF_PART));
  k1b_reduce<<<1, 256, 0, stream>>>(bn_g, bn_b, (const float*)(ws + OFF_PART),
                                    (float*)(ws + OFF_AB));
  k2_spike<<<dim3(NB, 9), 256, 0, stream>>>(x, conv_w, thrl1,
                                            (const float*)(ws + OFF_AB),
                                            (unsigned long long*)(ws + OFF_MASK));
  kp_fused<<<NGRP * BPG, 512, 0, stream>>>(ws, w_ih1, w_hh1, b_ih1, b_hh1, thr1,
                                           w_ih2, w_hh2, b_ih2, b_hh2, thr2);
  k3_head<<<NB, 128, 0, stream>>>((const float*)(ws + OFF_FEAT), fc_g_w, fc_g_b,
                                  fc_d1w, fc_d1b, thrdom, fc_d2w, fc_d2b, out);
}